// Round 13
// baseline (509.436 us; speedup 1.0000x reference)
//
#include <hip/hip_runtime.h>
#include <stdint.h>

typedef __attribute__((ext_vector_type(8))) short short8;    // MFMA A/B frag (8 bf16)
typedef __attribute__((ext_vector_type(4))) float floatx4;   // MFMA C/D frag

// ---------- bf16 helpers ----------
static __device__ __forceinline__ float b2f(uint16_t b){
    return __uint_as_float(((uint32_t)b) << 16);
}
static __device__ __forceinline__ uint16_t f2b(float f){
    uint32_t u = __float_as_uint(f);
    return (uint16_t)((u + 0x7fffu + ((u >> 16) & 1u)) >> 16);
}
static __device__ __forceinline__ float blo(uint32_t v){ return __uint_as_float(v << 16); }
static __device__ __forceinline__ float bhi(uint32_t v){ return __uint_as_float(v & 0xffff0000u); }
static __device__ __forceinline__ uint32_t pack2(float a, float b){
    return ((uint32_t)f2b(b) << 16) | (uint32_t)f2b(a);
}

// ---------- sentinel (only used when ws too small) ----------
__global__ void k_sentinel(uint32_t* out, int nwords, uint32_t pat){
    int i = blockIdx.x * blockDim.x + threadIdx.x;
    if (i < nwords) out[i] = pat;
}

// ---------- fused: zero deg[N] + zero stats[768]+hist[64] + dtype flags ----------
__global__ void k_zf(int* deg, int N, const uint32_t* xw, const int* ei, int* flags,
                     float* stats, int* hist, int ZB){
    if ((int)blockIdx.x == ZB){
        if (threadIdx.x != 0) return;
        int odd_nz = 0;
        for (int k = 0; k < 128; k++){
            if (ei[2 * k + 1] != 0) odd_nz = 1;
        }
        flags[0] = odd_nz ? 0 : 1;
        int big = 0;
        for (int k = 0; k < 128; k++){
            float lo = __uint_as_float(xw[k] << 16);
            if (!(fabsf(lo) <= 1024.0f)) big = 1;
        }
        flags[1] = big ? 0 : 1;
        return;
    }
    if ((int)blockIdx.x == ZB + 1){
        int t = threadIdx.x;
        #pragma unroll
        for (int j = 0; j < 3; j++) stats[j * 256 + t] = 0.f;
        if (t < 64) hist[t] = 0;
        return;
    }
    int i = blockIdx.x * blockDim.x + threadIdx.x;
    if (i < N) deg[i] = 0;
}

// ---------- CSR build: degree count + per-edge rank (rank makes k_fill atomic-free) ----------
__global__ void k_deg(const int* ei, int E, int* deg, uint16_t* rank, const int* flags){
    int e = blockIdx.x * blockDim.x + threadIdx.x;
    if (e < E){
        int d = flags[0] ? ei[2 * e] : ei[e];
        int r = atomicAdd(&deg[d], 1);
        rank[e] = (uint16_t)r;
    }
}

// ---------- block degree sums + degree histogram (64 bins, LDS-staged) ----------
__global__ void k_scan1(const int* deg, int N, int* bsum, int* hist){
    __shared__ int s[256];
    __shared__ int lh[64];
    int t = threadIdx.x;
    if (t < 64) lh[t] = 0;
    int i = blockIdx.x * 256 + t;
    int dv = (i < N) ? deg[i] : 0;
    s[t] = dv;
    __syncthreads();
    if (i < N){
        int b = dv < 63 ? dv : 63;
        atomicAdd(&lh[b], 1);
    }
    for (int off = 128; off > 0; off >>= 1){
        if (t < off) s[t] += s[t + off];
        __syncthreads();
    }
    if (t == 0) bsum[blockIdx.x] = s[0];
    if (t < 64 && lh[t]) atomicAdd(&hist[t], lh[t]);
}

__global__ void k_scan2(int* bsum, int nb, int* rp, int N,
                        const int* hist, int* hcur){
    __shared__ int s[512];
    int t = threadIdx.x;
    int v = (t < nb) ? bsum[t] : 0;
    s[t] = v;
    __syncthreads();
    for (int off = 1; off < 512; off <<= 1){
        int u = (t >= off) ? s[t - off] : 0;
        __syncthreads();
        s[t] += u;
        __syncthreads();
    }
    if (t < nb) bsum[t] = s[t] - v;
    if (t == 511) rp[N] = s[511];
    if (t == 0){                     // exclusive prefix of the 64-bin histogram
        int acc = 0;
        for (int b = 0; b < 64; b++){
            int c = hist[b];
            hcur[b] = acc;
            acc += c;
        }
    }
}

__global__ void k_scan3(const int* deg, int N, const int* bpre, int* rp){
    __shared__ int s[256];
    int t = threadIdx.x;
    int i = blockIdx.x * 256 + t;
    int v = (i < N) ? deg[i] : 0;
    s[t] = v;
    __syncthreads();
    for (int off = 1; off < 256; off <<= 1){
        int u = (t >= off) ? s[t - off] : 0;
        __syncthreads();
        s[t] += u;
        __syncthreads();
    }
    if (i < N) rp[i] = bpre[blockIdx.x] + s[t] - v;
}

// ---------- degree-binned permutation: rows sorted by degree bin ----------
// Block-level range reservation: LDS count per bin -> 1 global atomicAdd per
// (block,bin) to reserve a range -> LDS rank assigns positions. Order within a
// bin is nondeterministic (harmless: perm is only a processing order).
__global__ void k_perm(const int* __restrict__ deg, int N, int* __restrict__ hcur,
                       int* __restrict__ perm){
    __shared__ int lcnt[64], lbase[64], lcur[64];
    int t = threadIdx.x;
    if (t < 64){ lcnt[t] = 0; lcur[t] = 0; }
    __syncthreads();
    int i = blockIdx.x * 256 + t;
    int b = -1;
    if (i < N){
        int dv = deg[i];
        b = dv < 63 ? dv : 63;
        atomicAdd(&lcnt[b], 1);
    }
    __syncthreads();
    if (t < 64 && lcnt[t] > 0) lbase[t] = atomicAdd(&hcur[t], lcnt[t]);
    __syncthreads();
    if (i < N){
        int r = atomicAdd(&lcur[b], 1);
        perm[lbase[b] + r] = i;
    }
}

// ---------- fill: atomic-free, XCD-dst-sharded ----------
__global__ __launch_bounds__(256) void k_fill(const int* __restrict__ ei, int E,
                                              const int* __restrict__ rp,
                                              const uint16_t* __restrict__ rank,
                                              int* __restrict__ col,
                                              const int* __restrict__ flags, int N){
    int xcd = blockIdx.x & 7;
    int sub = blockIdx.x >> 3;
    int nsub = gridDim.x >> 3;
    int r0 = (int)(((long long)N * xcd) >> 3);
    int r1 = (int)(((long long)N * (xcd + 1)) >> 3);
    int e0 = (int)(((long long)E * sub) / nsub);
    int e1 = (int)(((long long)E * (sub + 1)) / nsub);
    int is64 = flags[0];
    for (int e = e0 + threadIdx.x; e < e1; e += 256){
        int d = is64 ? ei[2 * e] : ei[e];
        if (d >= r0 && d < r1){
            int sv = is64 ? ei[2 * (E + e)] : ei[E + e];
            int p = rp[d] + (int)rank[e];
            col[p] = sv;   // plain store: local L2 write-combines the line
        }
    }
}

// ---------- fused prep: W frags + bias cvt + x -> CHUNKED hx [8][N][16] ----------
__global__ void k_prep(const void* W0, const void* W1, const void* W2, const void* Wl,
                       uint16_t* Wf0, uint16_t* Wf1, uint16_t* Wf2, uint16_t* Wfl,
                       const void* b0, const void* b1, const void* b2, const void* bl,
                       float* bc, const void* x, uint16_t* hx, int N,
                       const int* flags){
    int blk = blockIdx.x;
    int t = threadIdx.x;
    if (blk >= 218){
        int nb = gridDim.x - 218;
        int bi = blk - 218;
        int half2 = N * 2;               // (row, half) pairs per chunk
        int isbf = flags[1];
        for (int c = 0; c < 8; c++){
            uint4* dst = (uint4*)(hx + (size_t)c * N * 16);
            if (isbf){
                const uint16_t* xb = (const uint16_t*)x;
                for (int idx = bi * 256 + t; idx < half2; idx += nb * 256){
                    int row = idx >> 1, h = idx & 1;
                    dst[idx] = *(const uint4*)(xb + (size_t)row * 128 + c * 16 + h * 8);
                }
            } else {
                const float* xf = (const float*)x;
                for (int idx = bi * 256 + t; idx < half2; idx += nb * 256){
                    int row = idx >> 1, h = idx & 1;
                    const float4* s = (const float4*)(xf + (size_t)row * 128 + c * 16 + h * 8);
                    float4 u0 = s[0];
                    float4 u1 = s[1];
                    uint4 o;
                    o.x = pack2(u0.x, u0.y); o.y = pack2(u0.z, u0.w);
                    o.z = pack2(u1.x, u1.y); o.w = pack2(u1.z, u1.w);
                    dst[idx] = o;
                }
            }
        }
        return;
    }
    if (blk >= 216){
        int i = (blk - 216) * 256 + t;
        if (i >= 424) return;
        const void* src; int li;
        if (i < 128)      { src = b0; li = i; }
        else if (i < 256) { src = b1; li = i - 128; }
        else if (i < 384) { src = b2; li = i - 256; }
        else              { src = bl; li = i - 384; }
        bc[i] = flags[1] ? b2f(((const uint16_t*)src)[li]) : ((const float*)src)[li];
        return;
    }
    const void* W; uint16_t* Wf; int C, ntiles, lb;
    if (blk < 64)        { W = W0; Wf = Wf0; C = 128; ntiles = 8; lb = blk; }
    else if (blk < 128)  { W = W1; Wf = Wf1; C = 128; ntiles = 8; lb = blk - 64; }
    else if (blk < 192)  { W = W2; Wf = Wf2; C = 128; ntiles = 8; lb = blk - 128; }
    else                 { W = Wl; Wf = Wfl; C = 40;  ntiles = 3; lb = blk - 192; }
    int idx = lb * 256 + t;
    int total = 4 * ntiles * 512;
    if (idx >= total) return;
    int j = idx & 7;
    int lane = (idx >> 3) & 63;
    int nt = (idx >> 9) % ntiles;
    int kt = idx / (512 * ntiles);
    int k = kt * 32 + (lane >> 4) * 8 + j;
    int n = nt * 16 + (lane & 15);
    uint16_t v = 0;
    if (n < C){
        v = flags[1] ? ((const uint16_t*)W)[k * C + n]
                     : f2b(((const float*)W)[k * C + n]);
    }
    Wf[idx] = v;
}

// ---------- CHUNKED aggregation, XCD-pinned chunks + DEGREE-BINNED row order ----------
// Round-12 verified: chunk=blockIdx&7 makes FETCH compulsory-only (46MB). Remaining
// cost was wave-straggler waste: a wave spans 32 rows and idles until the longest
// edge list finishes (E[max32 of Poisson(8)] ~ 2x mean -> VALUBusy 52%). Fix: rows
// processed in degree-sorted order (i = perm[idx]) so each wave holds ~equal-degree
// rows. Output written at ORIGINAL row i (perm only reorders processing); per-row
// summation order unchanged -> bit-identical results. Scattered 32B IO stays inside
// the chunk's XCD-pinned slab.
__global__ __launch_bounds__(256) void k_aggc(const uint16_t* __restrict__ Yin,
                                              const int* __restrict__ rp,
                                              const int* __restrict__ col,
                                              const int* __restrict__ perm,
                                              uint16_t* __restrict__ out,
                                              int N, int RT,
                                              const float* __restrict__ st,
                                              int apply_bn, float ninv){
    int t = threadIdx.x;
    int c = blockIdx.x & 7;          // chunk == XCD (round-robin dispatch heuristic)
    int tile = blockIdx.x >> 3;      // 0..RT-1
    int r = t >> 1, h = t & 1;
    int idx = tile * 128 + r;
    if (idx >= N) return;
    int i = perm[idx];               // degree-binned processing order
    float tt[8], iv[8];
    if (apply_bn){
        int f0 = c * 16 + h * 8;
        #pragma unroll
        for (int j = 0; j < 8; j++){
            float sv = st[f0 + j];
            float qv = st[128 + f0 + j];
            float m = sv * ninv;
            float var = qv * ninv - m * m;
            float ivj = rsqrtf(var + 1e-5f);
            iv[j] = ivj;
            tt[j] = -m * ivj;
        }
    }
    const uint4* base = (const uint4*)(Yin + (size_t)c * N * 16);
    int s0 = rp[i], e0 = rp[i + 1];
    float a[8];
    {   // self loop (peeled)
        uint4 w = base[(size_t)i * 2 + h];
        a[0] = blo(w.x); a[1] = bhi(w.x); a[2] = blo(w.y); a[3] = bhi(w.y);
        a[4] = blo(w.z); a[5] = bhi(w.z); a[6] = blo(w.w); a[7] = bhi(w.w);
        if (apply_bn){
            #pragma unroll
            for (int jj = 0; jj < 8; jj++) a[jj] = fmaxf(fmaf(a[jj], iv[jj], tt[jj]), 0.f);
        }
    }
    int k = s0;
    for (; k + 3 < e0; k += 4){     // 4 independent gathers in flight (proven depth)
        int j0 = col[k], j1 = col[k + 1], j2 = col[k + 2], j3 = col[k + 3];
        uint4 ww[4];
        ww[0] = base[(size_t)j0 * 2 + h];
        ww[1] = base[(size_t)j1 * 2 + h];
        ww[2] = base[(size_t)j2 * 2 + h];
        ww[3] = base[(size_t)j3 * 2 + h];
        #pragma unroll
        for (int u = 0; u < 4; u++){
            float v[8] = {blo(ww[u].x), bhi(ww[u].x), blo(ww[u].y), bhi(ww[u].y),
                          blo(ww[u].z), bhi(ww[u].z), blo(ww[u].w), bhi(ww[u].w)};
            if (apply_bn){
                #pragma unroll
                for (int jj = 0; jj < 8; jj++) v[jj] = fmaxf(fmaf(v[jj], iv[jj], tt[jj]), 0.f);
            }
            #pragma unroll
            for (int jj = 0; jj < 8; jj++) a[jj] += v[jj];
        }
    }
    for (; k < e0; k++){            // remainder 0..3 edges
        int j = col[k];
        uint4 w = base[(size_t)j * 2 + h];
        float v[8] = {blo(w.x), bhi(w.x), blo(w.y), bhi(w.y),
                      blo(w.z), bhi(w.z), blo(w.w), bhi(w.w)};
        if (apply_bn){
            #pragma unroll
            for (int jj = 0; jj < 8; jj++) v[jj] = fmaxf(fmaf(v[jj], iv[jj], tt[jj]), 0.f);
        }
        #pragma unroll
        for (int jj = 0; jj < 8; jj++) a[jj] += v[jj];
    }
    uint4 o;
    o.x = pack2(a[0], a[1]); o.y = pack2(a[2], a[3]);
    o.z = pack2(a[4], a[5]); o.w = pack2(a[6], a[7]);
    ((uint4*)(out + (size_t)c * N * 16))[(size_t)i * 2 + h] = o;
}

// ---------- MFMA GEMM (in place, CHUNKED A) + bias + per-block stats partials ----------
__global__ __launch_bounds__(256) void k_gemm(uint16_t* __restrict__ A,
                                              const uint16_t* __restrict__ Wf,
                                              const float* __restrict__ bias,
                                              float* __restrict__ part, int N){
    __shared__ __align__(16) uint16_t wlds[16384];
    __shared__ float sh_sum[128], sh_ssq[128];
    int t = threadIdx.x;
    if (t < 128){ sh_sum[t] = 0.f; sh_ssq[t] = 0.f; }
    {
        const uint4* s = (const uint4*)Wf;
        uint4* d = (uint4*)wlds;
        for (int i = t; i < 2048; i += 256) d[i] = s[i];
    }
    __syncthreads();
    int lane = t & 63, wave = t >> 6;
    int m = lane & 15, q = lane >> 4;
    int rb[2];
    rb[0] = blockIdx.x * 128 + wave * 16;
    rb[1] = rb[0] + 64;
    short8 afrag[2][4];
    #pragma unroll
    for (int mt = 0; mt < 2; mt++){
        int arow = rb[mt] + m;
        if (arow >= N) arow = N - 1;
        #pragma unroll
        for (int kt = 0; kt < 4; kt++){
            int cc = 2 * kt + (q >> 1);
            afrag[mt][kt] = *(const short8*)(A + (size_t)cc * N * 16
                                               + (size_t)arow * 16 + (q & 1) * 8);
        }
    }
    floatx4 acc[2][8];
    #pragma unroll
    for (int mt = 0; mt < 2; mt++)
        #pragma unroll
        for (int nt = 0; nt < 8; nt++) acc[mt][nt] = (floatx4){0.f, 0.f, 0.f, 0.f};
    const short8* wl = (const short8*)wlds;
    #pragma unroll
    for (int kt = 0; kt < 4; kt++){
        #pragma unroll
        for (int nt = 0; nt < 8; nt++){
            short8 bfrag = wl[(kt * 8 + nt) * 64 + lane];
            #pragma unroll
            for (int mt = 0; mt < 2; mt++){
                acc[mt][nt] = __builtin_amdgcn_mfma_f32_16x16x32_bf16(afrag[mt][kt], bfrag, acc[mt][nt], 0, 0, 0);
            }
        }
    }
    #pragma unroll
    for (int mt = 0; mt < 2; mt++){
        #pragma unroll
        for (int nt = 0; nt < 8; nt++){
            int ccol = nt * 16 + m;
            float bv = bias[ccol];
            float s = 0.f, ss = 0.f;
            #pragma unroll
            for (int r = 0; r < 4; r++){
                int grow = rb[mt] + q * 4 + r;
                if (grow < N){
                    float y = acc[mt][nt][r] + bv;
                    A[(size_t)nt * N * 16 + (size_t)grow * 16 + m] = f2b(y);
                    s += y;
                    ss += y * y;
                }
            }
            s += __shfl_xor(s, 16); s += __shfl_xor(s, 32);
            ss += __shfl_xor(ss, 16); ss += __shfl_xor(ss, 32);
            if (q == 0){
                atomicAdd(&sh_sum[ccol], s);
                atomicAdd(&sh_ssq[ccol], ss);
            }
        }
    }
    __syncthreads();
    if (t < 128){
        part[(size_t)blockIdx.x * 256 + t] = sh_sum[t];
        part[(size_t)blockIdx.x * 256 + 128 + t] = sh_ssq[t];
    }
}

// ---------- reduce per-block partials -> st[256] (flat, coalesced, atomic finish) ----------
__global__ __launch_bounds__(256) void k_red(const float* __restrict__ part, int nb,
                                             float* __restrict__ st){
    int t = threadIdx.x;
    int r0 = blockIdx.x * 32;
    int r1 = r0 + 32; if (r1 > nb) r1 = nb;
    float s0 = 0.f, s1 = 0.f, s2 = 0.f, s3 = 0.f;
    int b = r0;
    for (; b + 3 < r1; b += 4){
        s0 += part[(size_t)b * 256 + t];
        s1 += part[(size_t)(b + 1) * 256 + t];
        s2 += part[(size_t)(b + 2) * 256 + t];
        s3 += part[(size_t)(b + 3) * 256 + t];
    }
    for (; b < r1; b++) s0 += part[(size_t)b * 256 + t];
    atomicAdd(&st[t], (s0 + s1) + (s2 + s3));
}

// ---------- final GEMM with BN+ReLU applied to CHUNKED A on read ----------
__global__ __launch_bounds__(256) void k_out(const uint16_t* __restrict__ A,
                                             const uint16_t* __restrict__ Wf,
                                             const float* __restrict__ bias,
                                             const float* __restrict__ st, float ninv,
                                             void* __restrict__ out, int N,
                                             const int* __restrict__ flags){
    __shared__ __align__(16) uint16_t wlds[6144];
    __shared__ float s_m[128], s_iv[128];
    int t = threadIdx.x;
    {
        const uint4* s = (const uint4*)Wf;
        uint4* d = (uint4*)wlds;
        for (int i = t; i < 768; i += 256) d[i] = s[i];
    }
    if (t < 128){
        float m = st[t] * ninv;
        float var = st[128 + t] * ninv - m * m;
        s_m[t] = m;
        s_iv[t] = rsqrtf(var + 1e-5f);
    }
    __syncthreads();
    int lane = t & 63, wave = t >> 6;
    int m = lane & 15, q = lane >> 4;
    int row_base = blockIdx.x * 64 + wave * 16;
    int arow = row_base + m;
    if (arow >= N) arow = N - 1;
    short8 afrag[4];
    #pragma unroll
    for (int kt = 0; kt < 4; kt++){
        uint4 u = *(const uint4*)(A + (size_t)(2 * kt + (q >> 1)) * N * 16
                                    + (size_t)arow * 16 + (q & 1) * 8);
        float v[8] = {blo(u.x), bhi(u.x), blo(u.y), bhi(u.y),
                      blo(u.z), bhi(u.z), blo(u.w), bhi(u.w)};
        int c0 = kt * 32 + q * 8;
        #pragma unroll
        for (int j = 0; j < 8; j++) v[j] = fmaxf((v[j] - s_m[c0 + j]) * s_iv[c0 + j], 0.f);
        uint4 o;
        o.x = pack2(v[0], v[1]); o.y = pack2(v[2], v[3]);
        o.z = pack2(v[4], v[5]); o.w = pack2(v[6], v[7]);
        afrag[kt] = *(short8*)&o;
    }
    floatx4 acc[3];
    #pragma unroll
    for (int nt = 0; nt < 3; nt++) acc[nt] = (floatx4){0.f, 0.f, 0.f, 0.f};
    const short8* wl = (const short8*)wlds;
    #pragma unroll
    for (int kt = 0; kt < 4; kt++){
        #pragma unroll
        for (int nt = 0; nt < 3; nt++){
            acc[nt] = __builtin_amdgcn_mfma_f32_16x16x32_bf16(afrag[kt], wl[(kt * 3 + nt) * 64 + lane], acc[nt], 0, 0, 0);
        }
    }
    int isbf = flags[1];
    #pragma unroll
    for (int nt = 0; nt < 3; nt++){
        int ccol = nt * 16 + m;
        if (ccol < 40){
            float bv = bias[ccol];
            #pragma unroll
            for (int r = 0; r < 4; r++){
                int grow = row_base + q * 4 + r;
                if (grow < N){
                    float y = acc[nt][r] + bv;
                    if (isbf) ((uint16_t*)out)[(size_t)grow * 40 + ccol] = f2b(y);
                    else      ((float*)out)[(size_t)grow * 40 + ccol] = y;
                }
            }
        }
    }
}

extern "C" void kernel_launch(void* const* d_in, const int* in_sizes, int n_in,
                              void* d_out, int out_size, void* d_ws, size_t ws_size,
                              hipStream_t stream){
    (void)n_in;
    const void* x  = d_in[0];
    const int* ei  = (const int*)d_in[1];
    const void* W0 = d_in[2];
    const void* b0 = d_in[3];
    const void* W1 = d_in[4];
    const void* b1 = d_in[5];
    const void* W2 = d_in[6];
    const void* b2 = d_in[7];
    const void* Wl = d_in[8];
    const void* bl = d_in[9];

    const int N = in_sizes[0] / 128;
    const int E = in_sizes[1] / 2;
    const int NF = N * 128;
    const int NB = (N + 255) / 256;
    const int RT = (N + 127) / 128;             // row-tiles per chunk (k_aggc, k_gemm)
    const int aggc_grid    = 8 * RT;            // chunk = blockIdx&7 (XCD-pinned)
    const int gemm_blocks2 = RT;                // k_gemm blocks (128 rows each)
    const int gemm_blocks  = (N + 63) / 64;     // k_out blocks
    const int red_blocks   = (gemm_blocks2 + 31) / 32;

    // ---- workspace layout ----
    char* ws = (char*)d_ws;
    size_t off = 0;
    uint16_t* hx = (uint16_t*)(ws + off); off += ((size_t)NF * 2 + 255) & ~(size_t)255;
    uint16_t* ag = (uint16_t*)(ws + off); off += ((size_t)NF * 2 + 255) & ~(size_t)255;
    int* col     = (int*)(ws + off);      off += ((size_t)E * 4 + 255) & ~(size_t)255;
    int* rp      = (int*)(ws + off);      off += ((size_t)(N + 1) * 4 + 255) & ~(size_t)255;
    uint16_t* rank = (uint16_t*)(ws + off); off += ((size_t)E * 2 + 255) & ~(size_t)255;
    int* deg     = (int*)(ws + off);      off += ((size_t)N * 4 + 255) & ~(size_t)255;
    int* perm    = (int*)(ws + off);      off += ((size_t)N * 4 + 255) & ~(size_t)255;
    int* bsum    = (int*)(ws + off);      off += 512 * 4;
    int* flags   = (int*)(ws + off);      off += 256;
    int* hist    = (int*)(ws + off);      off += 64 * 4;
    int* hcur    = (int*)(ws + off);      off += 64 * 4 + 128;
    uint16_t* Wf0 = (uint16_t*)(ws + off); off += 16384 * 2;
    uint16_t* Wf1 = (uint16_t*)(ws + off); off += 16384 * 2;
    uint16_t* Wf2 = (uint16_t*)(ws + off); off += 16384 * 2;
    uint16_t* Wfl = (uint16_t*)(ws + off); off += 6144 * 2;
    float* bc    = (float*)(ws + off);    off += 424 * 4 + 160;
    float* stats = (float*)(ws + off);    off += 768 * 4;   // 3 layers x (sum[128], ssq[128])
    float* part  = (float*)(ws + off);    off += (size_t)gemm_blocks2 * 256 * 4;
    const size_t required = off;

    if (ws_size < required){
        int nwords = out_size / 2;
        k_sentinel<<<(nwords + 255) / 256, 256, 0, stream>>>((uint32_t*)d_out, nwords, 0x40004000u);
        return;
    }

    // ---- flags + zeroing (fused), CSR build + degree-binned permutation ----
    k_zf<<<NB + 2, 256, 0, stream>>>(deg, N, (const uint32_t*)x, ei, flags, stats, hist, NB);
    k_deg<<<(E + 255) / 256, 256, 0, stream>>>(ei, E, deg, rank, flags);
    k_scan1<<<NB, 256, 0, stream>>>(deg, N, bsum, hist);
    k_scan2<<<1, 512, 0, stream>>>(bsum, NB, rp, N, hist, hcur);
    k_scan3<<<NB, 256, 0, stream>>>(deg, N, bsum, rp);
    k_perm<<<NB, 256, 0, stream>>>(deg, N, hcur, perm);
    k_fill<<<1024, 256, 0, stream>>>(ei, E, rp, rank, col, flags, N);

    // ---- fused conversions / weight prep (x always converted into chunked hx) ----
    k_prep<<<2266, 256, 0, stream>>>(W0, W1, W2, Wl, Wf0, Wf1, Wf2, Wfl,
                                     b0, b1, b2, bl, bc, x, hx, N, flags);

    const float ninv = 1.0f / (float)N;

    // layer 0: agg(x) -> ag (chunked), gemm in place (Y0 in ag), stats0
    k_aggc<<<aggc_grid, 256, 0, stream>>>(hx, rp, col, perm, ag, N, RT, stats, 0, ninv);
    k_gemm<<<gemm_blocks2, 256, 0, stream>>>(ag, Wf0, bc, part, N);
    k_red<<<red_blocks, 256, 0, stream>>>(part, gemm_blocks2, stats);
    // layer 1: agg(bn0(Y0)) -> hx, gemm in place (Y1 in hx), stats1
    k_aggc<<<aggc_grid, 256, 0, stream>>>(ag, rp, col, perm, hx, N, RT, stats, 1, ninv);
    k_gemm<<<gemm_blocks2, 256, 0, stream>>>(hx, Wf1, bc + 128, part, N);
    k_red<<<red_blocks, 256, 0, stream>>>(part, gemm_blocks2, stats + 256);
    // layer 2: agg(bn1(Y1)) -> ag, gemm in place (Y2 in ag), stats2
    k_aggc<<<aggc_grid, 256, 0, stream>>>(hx, rp, col, perm, ag, N, RT, stats + 256, 1, ninv);
    k_gemm<<<gemm_blocks2, 256, 0, stream>>>(ag, Wf2, bc + 256, part, N);
    k_red<<<red_blocks, 256, 0, stream>>>(part, gemm_blocks2, stats + 512);
    // final: out = bn2(Y2)relu @ Wl + bl
    k_out<<<gemm_blocks, 256, 0, stream>>>(ag, Wfl, bc + 384, stats + 512, ninv, d_out, N, flags);
}

// Round 14
// 373.722 us; speedup vs baseline: 1.3631x; 1.3631x over previous
//
#include <hip/hip_runtime.h>
#include <stdint.h>

typedef __attribute__((ext_vector_type(8))) short short8;    // MFMA A/B frag (8 bf16)
typedef __attribute__((ext_vector_type(4))) float floatx4;   // MFMA C/D frag

// ---------- bf16 helpers ----------
static __device__ __forceinline__ float b2f(uint16_t b){
    return __uint_as_float(((uint32_t)b) << 16);
}
static __device__ __forceinline__ uint16_t f2b(float f){
    uint32_t u = __float_as_uint(f);
    return (uint16_t)((u + 0x7fffu + ((u >> 16) & 1u)) >> 16);
}
static __device__ __forceinline__ float blo(uint32_t v){ return __uint_as_float(v << 16); }
static __device__ __forceinline__ float bhi(uint32_t v){ return __uint_as_float(v & 0xffff0000u); }
static __device__ __forceinline__ uint32_t pack2(float a, float b){
    return ((uint32_t)f2b(b) << 16) | (uint32_t)f2b(a);
}

// ---------- sentinel (only used when ws too small) ----------
__global__ void k_sentinel(uint32_t* out, int nwords, uint32_t pat){
    int i = blockIdx.x * blockDim.x + threadIdx.x;
    if (i < nwords) out[i] = pat;
}

// ---------- fused: zero deg[N] + zero stats[768] + dtype flags ----------
// blocks [0,ZB): zero deg; block ZB: flags; block ZB+1: zero stats (ws is poisoned)
__global__ void k_zf(int* deg, int N, const uint32_t* xw, const int* ei, int* flags,
                     float* stats, int ZB){
    if ((int)blockIdx.x == ZB){
        if (threadIdx.x != 0) return;
        int odd_nz = 0;
        for (int k = 0; k < 128; k++){
            if (ei[2 * k + 1] != 0) odd_nz = 1;
        }
        flags[0] = odd_nz ? 0 : 1;
        int big = 0;
        for (int k = 0; k < 128; k++){
            float lo = __uint_as_float(xw[k] << 16);
            if (!(fabsf(lo) <= 1024.0f)) big = 1;
        }
        flags[1] = big ? 0 : 1;
        return;
    }
    if ((int)blockIdx.x == ZB + 1){
        int t = threadIdx.x;
        #pragma unroll
        for (int j = 0; j < 3; j++) stats[j * 256 + t] = 0.f;
        return;
    }
    int i = blockIdx.x * blockDim.x + threadIdx.x;
    if (i < N) deg[i] = 0;
}

// ---------- CSR build: degree count + per-edge rank (rank makes k_fill atomic-free) ----------
__global__ void k_deg(const int* ei, int E, int* deg, uint16_t* rank, const int* flags){
    int e = blockIdx.x * blockDim.x + threadIdx.x;
    if (e < E){
        int d = flags[0] ? ei[2 * e] : ei[e];
        int r = atomicAdd(&deg[d], 1);
        rank[e] = (uint16_t)r;
    }
}

__global__ void k_scan1(const int* deg, int N, int* bsum){
    __shared__ int s[256];
    int t = threadIdx.x;
    int i = blockIdx.x * 256 + t;
    s[t] = (i < N) ? deg[i] : 0;
    __syncthreads();
    for (int off = 128; off > 0; off >>= 1){
        if (t < off) s[t] += s[t + off];
        __syncthreads();
    }
    if (t == 0) bsum[blockIdx.x] = s[0];
}

__global__ void k_scan2(int* bsum, int nb, int* rp, int N){
    __shared__ int s[512];
    int t = threadIdx.x;
    int v = (t < nb) ? bsum[t] : 0;
    s[t] = v;
    __syncthreads();
    for (int off = 1; off < 512; off <<= 1){
        int u = (t >= off) ? s[t - off] : 0;
        __syncthreads();
        s[t] += u;
        __syncthreads();
    }
    if (t < nb) bsum[t] = s[t] - v;
    if (t == 511) rp[N] = s[511];
}

__global__ void k_scan3(const int* deg, int N, const int* bpre, int* rp){
    __shared__ int s[256];
    int t = threadIdx.x;
    int i = blockIdx.x * 256 + t;
    int v = (i < N) ? deg[i] : 0;
    s[t] = v;
    __syncthreads();
    for (int off = 1; off < 256; off <<= 1){
        int u = (t >= off) ? s[t - off] : 0;
        __syncthreads();
        s[t] += u;
        __syncthreads();
    }
    if (i < N) rp[i] = bpre[blockIdx.x] + s[t] - v;
}

// ---------- fill: atomic-free, XCD-dst-sharded ----------
// Block b assumes XCD (b&7); the 8 blocks sharing edge-chunk (b>>3) each keep edges whose
// dst falls in their N/8 range, so all stores to a 64B line of col[] come from ONE XCD's
// L2 (kills the 18x write amplification seen in round 0). ei re-reads ride L3.
__global__ __launch_bounds__(256) void k_fill(const int* __restrict__ ei, int E,
                                              const int* __restrict__ rp,
                                              const uint16_t* __restrict__ rank,
                                              int* __restrict__ col,
                                              const int* __restrict__ flags, int N){
    int xcd = blockIdx.x & 7;
    int sub = blockIdx.x >> 3;
    int nsub = gridDim.x >> 3;
    int r0 = (int)(((long long)N * xcd) >> 3);
    int r1 = (int)(((long long)N * (xcd + 1)) >> 3);
    int e0 = (int)(((long long)E * sub) / nsub);
    int e1 = (int)(((long long)E * (sub + 1)) / nsub);
    int is64 = flags[0];
    for (int e = e0 + threadIdx.x; e < e1; e += 256){
        int d = is64 ? ei[2 * e] : ei[e];
        if (d >= r0 && d < r1){
            int sv = is64 ? ei[2 * (E + e)] : ei[E + e];
            int p = rp[d] + (int)rank[e];
            col[p] = sv;   // plain store: local L2 write-combines the line
        }
    }
}

// ---------- fused prep: W fragment reorders + bias cvt + x cvt in ONE launch ----------
// blocks [0,216): weight frags; [216,218): bias; [218,...): x f32->bf16 vectorized
__global__ void k_prep(const void* W0, const void* W1, const void* W2, const void* Wl,
                       uint16_t* Wf0, uint16_t* Wf1, uint16_t* Wf2, uint16_t* Wfl,
                       const void* b0, const void* b1, const void* b2, const void* bl,
                       float* bc, const void* x, uint16_t* hx, int NF,
                       const int* flags){
    int blk = blockIdx.x;
    int t = threadIdx.x;
    if (blk >= 218){
        if (flags[1]) return;   // layer-0 k_ag reads raw x directly in bf16 case
        int nb = gridDim.x - 218;
        int n8 = NF >> 3;       // NF is a multiple of 8 (F=128)
        const float4* xv = (const float4*)x;
        uint4* hv = (uint4*)hx;
        for (int i = (blk - 218) * 256 + t; i < n8; i += nb * 256){
            float4 u0 = xv[i * 2];
            float4 u1 = xv[i * 2 + 1];
            uint4 o;
            o.x = pack2(u0.x, u0.y); o.y = pack2(u0.z, u0.w);
            o.z = pack2(u1.x, u1.y); o.w = pack2(u1.z, u1.w);
            hv[i] = o;
        }
        return;
    }
    if (blk >= 216){
        int i = (blk - 216) * 256 + t;
        if (i >= 424) return;
        const void* src; int li;
        if (i < 128)      { src = b0; li = i; }
        else if (i < 256) { src = b1; li = i - 128; }
        else if (i < 384) { src = b2; li = i - 256; }
        else              { src = bl; li = i - 384; }
        bc[i] = flags[1] ? b2f(((const uint16_t*)src)[li]) : ((const float*)src)[li];
        return;
    }
    const void* W; uint16_t* Wf; int C, ntiles, lb;
    if (blk < 64)        { W = W0; Wf = Wf0; C = 128; ntiles = 8; lb = blk; }
    else if (blk < 128)  { W = W1; Wf = Wf1; C = 128; ntiles = 8; lb = blk - 64; }
    else if (blk < 192)  { W = W2; Wf = Wf2; C = 128; ntiles = 8; lb = blk - 128; }
    else                 { W = Wl; Wf = Wfl; C = 40;  ntiles = 3; lb = blk - 192; }
    int idx = lb * 256 + t;
    int total = 4 * ntiles * 512;
    if (idx >= total) return;
    int j = idx & 7;
    int lane = (idx >> 3) & 63;
    int nt = (idx >> 9) % ntiles;
    int kt = idx / (512 * ntiles);
    int k = kt * 32 + (lane >> 4) * 8 + j;
    int n = nt * 16 + (lane & 15);
    uint16_t v = 0;
    if (n < C){
        v = flags[1] ? ((const uint16_t*)W)[k * C + n]
                     : f2b(((const float*)W)[k * C + n]);
    }
    Wf[idx] = v;
}

// ---------- FUSED aggregate + MFMA GEMM + bias + stats partials ----------
// Block = 256 threads = one 16-row tile. Phase 1 (proven round-2 gather): thread
// (r = t>>4, c = t&15) accumulates a[8] = features [c*8,+8) of aggregated row r with
// lazy BN+ReLU on read. Phase 2: tile bounces through 4KB XOR-swizzled LDS into MFMA
// A-frag layout; 8 MFMA per wave (2 n-tiles x 4 k-tiles); B-frags read straight from
// the L2-hot 32KB Wf. Saves the 51.2MB ag round-trip + 1 dispatch per layer.
// SESSION VERDICT (rounds 2-13, all falsified vs this shape): no deeper gather
// pipeline (r3: occupancy loss), no wave-private MFMA (r6: VGPR-64 cliff), no
// persistent grid (r9: occupancy drop), no src-stripe sort (r2: FETCH unchanged),
// no feature-chunking (r12: straggler-bound), no degree-binned perm (r13: scattered
// writes thrash L2, FETCH 46->221MB). This exact kernel measured 373.7 / 375.6 us.
__global__ __launch_bounds__(256) void k_ag(const uint16_t* __restrict__ Yin,
                                            const uint16_t* __restrict__ xraw,
                                            const int* __restrict__ rp,
                                            const int* __restrict__ col,
                                            uint16_t* __restrict__ Yout,
                                            const uint16_t* __restrict__ Wf,
                                            const float* __restrict__ bias,
                                            float* __restrict__ part, int N,
                                            const float* __restrict__ st,
                                            int apply_bn, float ninv,
                                            const int* __restrict__ flags){
    __shared__ __align__(16) uint16_t albs[2048];   // 16 x 128 bf16, XOR-swizzled
    __shared__ float sh_sum[128], sh_ssq[128];
    int t = threadIdx.x;
    if (t < 128){ sh_sum[t] = 0.f; sh_ssq[t] = 0.f; }
    int l16 = t & 15;
    int r = t >> 4;
    int row = blockIdx.x * 16 + r;
    int i = (row < N) ? row : N - 1;    // clamp (no early return: block syncs below)
    float tt[8], iv[8];
    const uint16_t* src = Yin;
    if (apply_bn){
        int f0 = l16 * 8;
        #pragma unroll
        for (int j = 0; j < 8; j++){
            float sv = st[f0 + j];
            float qv = st[128 + f0 + j];
            float m = sv * ninv;
            float var = qv * ninv - m * m;
            float ivj = rsqrtf(var + 1e-5f);
            iv[j] = ivj;
            tt[j] = -m * ivj;
        }
    } else if (flags[1]){
        src = xraw;
    }
    const uint4* base = (const uint4*)src;
    int s0 = rp[i], e0 = rp[i + 1];
    float a[8];
    {   // self loop (peeled out of the neighbor loop)
        uint4 w = base[(size_t)i * 16 + l16];
        a[0] = blo(w.x); a[1] = bhi(w.x); a[2] = blo(w.y); a[3] = bhi(w.y);
        a[4] = blo(w.z); a[5] = bhi(w.z); a[6] = blo(w.w); a[7] = bhi(w.w);
        if (apply_bn){
            #pragma unroll
            for (int jj = 0; jj < 8; jj++) a[jj] = fmaxf(fmaf(a[jj], iv[jj], tt[jj]), 0.f);
        }
    }
    int k = s0;
    for (; k + 3 < e0; k += 4){     // 4 independent row gathers in flight (round-2 proven)
        int j0 = col[k], j1 = col[k + 1], j2 = col[k + 2], j3 = col[k + 3];
        uint4 ww[4];
        ww[0] = base[(size_t)j0 * 16 + l16];
        ww[1] = base[(size_t)j1 * 16 + l16];
        ww[2] = base[(size_t)j2 * 16 + l16];
        ww[3] = base[(size_t)j3 * 16 + l16];
        #pragma unroll
        for (int u = 0; u < 4; u++){
            float v[8] = {blo(ww[u].x), bhi(ww[u].x), blo(ww[u].y), bhi(ww[u].y),
                          blo(ww[u].z), bhi(ww[u].z), blo(ww[u].w), bhi(ww[u].w)};
            if (apply_bn){
                #pragma unroll
                for (int jj = 0; jj < 8; jj++) v[jj] = fmaxf(fmaf(v[jj], iv[jj], tt[jj]), 0.f);
            }
            #pragma unroll
            for (int jj = 0; jj < 8; jj++) a[jj] += v[jj];
        }
    }
    for (; k < e0; k++){            // remainder 0..3 edges
        int j = col[k];
        uint4 w = base[(size_t)j * 16 + l16];
        float v[8] = {blo(w.x), bhi(w.x), blo(w.y), bhi(w.y),
                      blo(w.z), bhi(w.z), blo(w.w), bhi(w.w)};
        if (apply_bn){
            #pragma unroll
            for (int jj = 0; jj < 8; jj++) v[jj] = fmaxf(fmaf(v[jj], iv[jj], tt[jj]), 0.f);
        }
        #pragma unroll
        for (int jj = 0; jj < 8; jj++) a[jj] += v[jj];
    }
    {   // pack to bf16 and drop into swizzled LDS (row r, bytes [l16*16,+16))
        uint4 o;
        o.x = pack2(a[0], a[1]); o.y = pack2(a[2], a[3]);
        o.z = pack2(a[4], a[5]); o.w = pack2(a[6], a[7]);
        int wb = r * 256 + ((l16 * 16) ^ ((r & 7) << 4));
        *(uint4*)((char*)albs + wb) = o;
    }
    __syncthreads();
    // ---- MFMA phase: wave w computes n-tiles {2w, 2w+1} of the 16x128 output ----
    int lane = t & 63, wave = t >> 6;
    int m = lane & 15, q = lane >> 4;
    short8 af[4];
    #pragma unroll
    for (int kt = 0; kt < 4; kt++){
        int rb = m * 256 + ((kt * 64 + q * 16) ^ ((m & 7) << 4));
        af[kt] = *(const short8*)((const char*)albs + rb);
    }
    const short8* wg = (const short8*)Wf;
    floatx4 acc[2];
    acc[0] = (floatx4){0.f, 0.f, 0.f, 0.f};
    acc[1] = (floatx4){0.f, 0.f, 0.f, 0.f};
    #pragma unroll
    for (int kt = 0; kt < 4; kt++){
        #pragma unroll
        for (int n2 = 0; n2 < 2; n2++){
            short8 bf = wg[(kt * 8 + wave * 2 + n2) * 64 + lane];
            acc[n2] = __builtin_amdgcn_mfma_f32_16x16x32_bf16(af[kt], bf, acc[n2], 0, 0, 0);
        }
    }
    int row_base = blockIdx.x * 16;
    #pragma unroll
    for (int n2 = 0; n2 < 2; n2++){
        int ccol = (wave * 2 + n2) * 16 + m;
        float bv = bias[ccol];
        float s = 0.f, ss = 0.f;
        #pragma unroll
        for (int rr = 0; rr < 4; rr++){
            int grow = row_base + q * 4 + rr;
            if (grow < N){
                float y = acc[n2][rr] + bv;
                Yout[(size_t)grow * 128 + ccol] = f2b(y);
                s += y;
                ss += y * y;
            }
        }
        s += __shfl_xor(s, 16); s += __shfl_xor(s, 32);
        ss += __shfl_xor(ss, 16); ss += __shfl_xor(ss, 32);
        if (q == 0){
            atomicAdd(&sh_sum[ccol], s);
            atomicAdd(&sh_ssq[ccol], ss);
        }
    }
    __syncthreads();
    if (t < 128){
        part[(size_t)blockIdx.x * 256 + t] = sh_sum[t];
        part[(size_t)blockIdx.x * 256 + 128 + t] = sh_ssq[t];
    }
}

// ---------- reduce per-block partials -> st[256] ----------
// Flat grid: block b reduces rows [b*32, b*32+32) of part for ALL 256 columns.
// Thread t owns column t -> every row read is 1KB contiguous (fully coalesced).
// 4 accumulators for load ILP; one atomicAdd per thread into the pre-zeroed st.
__global__ __launch_bounds__(256) void k_red(const float* __restrict__ part, int nb,
                                             float* __restrict__ st){
    int t = threadIdx.x;
    int r0 = blockIdx.x * 32;
    int r1 = r0 + 32; if (r1 > nb) r1 = nb;
    float s0 = 0.f, s1 = 0.f, s2 = 0.f, s3 = 0.f;
    int b = r0;
    for (; b + 3 < r1; b += 4){
        s0 += part[(size_t)b * 256 + t];
        s1 += part[(size_t)(b + 1) * 256 + t];
        s2 += part[(size_t)(b + 2) * 256 + t];
        s3 += part[(size_t)(b + 3) * 256 + t];
    }
    for (; b < r1; b++) s0 += part[(size_t)b * 256 + t];
    atomicAdd(&st[t], (s0 + s1) + (s2 + s3));
}

// ---------- final GEMM with BN+ReLU applied to A on read ----------
__global__ __launch_bounds__(256) void k_out(const uint16_t* __restrict__ A,
                                             const uint16_t* __restrict__ Wf,
                                             const float* __restrict__ bias,
                                             const float* __restrict__ st, float ninv,
                                             void* __restrict__ out, int N,
                                             const int* __restrict__ flags){
    __shared__ __align__(16) uint16_t wlds[6144];
    __shared__ float s_m[128], s_iv[128];
    int t = threadIdx.x;
    {
        const uint4* s = (const uint4*)Wf;
        uint4* d = (uint4*)wlds;
        for (int i = t; i < 768; i += 256) d[i] = s[i];
    }
    if (t < 128){
        float m = st[t] * ninv;
        float var = st[128 + t] * ninv - m * m;
        s_m[t] = m;
        s_iv[t] = rsqrtf(var + 1e-5f);
    }
    __syncthreads();
    int lane = t & 63, wave = t >> 6;
    int m = lane & 15, q = lane >> 4;
    int row_base = blockIdx.x * 64 + wave * 16;
    int arow = row_base + m;
    if (arow >= N) arow = N - 1;
    short8 afrag[4];
    const uint4* ap = (const uint4*)(A + (size_t)arow * 128);
    #pragma unroll
    for (int kt = 0; kt < 4; kt++){
        uint4 u = ap[kt * 4 + q];
        float v[8] = {blo(u.x), bhi(u.x), blo(u.y), bhi(u.y),
                      blo(u.z), bhi(u.z), blo(u.w), bhi(u.w)};
        int c0 = kt * 32 + q * 8;
        #pragma unroll
        for (int j = 0; j < 8; j++) v[j] = fmaxf((v[j] - s_m[c0 + j]) * s_iv[c0 + j], 0.f);
        uint4 o;
        o.x = pack2(v[0], v[1]); o.y = pack2(v[2], v[3]);
        o.z = pack2(v[4], v[5]); o.w = pack2(v[6], v[7]);
        afrag[kt] = *(short8*)&o;
    }
    floatx4 acc[3];
    #pragma unroll
    for (int nt = 0; nt < 3; nt++) acc[nt] = (floatx4){0.f, 0.f, 0.f, 0.f};
    const short8* wl = (const short8*)wlds;
    #pragma unroll
    for (int kt = 0; kt < 4; kt++){
        #pragma unroll
        for (int nt = 0; nt < 3; nt++){
            acc[nt] = __builtin_amdgcn_mfma_f32_16x16x32_bf16(afrag[kt], wl[(kt * 3 + nt) * 64 + lane], acc[nt], 0, 0, 0);
        }
    }
    int isbf = flags[1];
    #pragma unroll
    for (int nt = 0; nt < 3; nt++){
        int ccol = nt * 16 + m;
        if (ccol < 40){
            float bv = bias[ccol];
            #pragma unroll
            for (int r = 0; r < 4; r++){
                int grow = row_base + q * 4 + r;
                if (grow < N){
                    float y = acc[nt][r] + bv;
                    if (isbf) ((uint16_t*)out)[(size_t)grow * 40 + ccol] = f2b(y);
                    else      ((float*)out)[(size_t)grow * 40 + ccol] = y;
                }
            }
        }
    }
}

extern "C" void kernel_launch(void* const* d_in, const int* in_sizes, int n_in,
                              void* d_out, int out_size, void* d_ws, size_t ws_size,
                              hipStream_t stream){
    (void)n_in;
    const void* x  = d_in[0];
    const int* ei  = (const int*)d_in[1];
    const void* W0 = d_in[2];
    const void* b0 = d_in[3];
    const void* W1 = d_in[4];
    const void* b1 = d_in[5];
    const void* W2 = d_in[6];
    const void* b2 = d_in[7];
    const void* Wl = d_in[8];
    const void* bl = d_in[9];

    const int N = in_sizes[0] / 128;
    const int E = in_sizes[1] / 2;
    const int NF = N * 128;
    const int NB = (N + 255) / 256;
    const int agg_blocks  = (N + 15) / 16;      // fused agg+gemm blocks (16 rows each)
    const int gemm_blocks = (N + 63) / 64;      // k_out blocks
    const int red_blocks  = (agg_blocks + 31) / 32;

    // ---- workspace layout ----
    char* ws = (char*)d_ws;
    size_t off = 0;
    uint16_t* hx = (uint16_t*)(ws + off); off += ((size_t)NF * 2 + 255) & ~(size_t)255;
    uint16_t* ag = (uint16_t*)(ws + off); off += ((size_t)NF * 2 + 255) & ~(size_t)255;
    int* col     = (int*)(ws + off);      off += ((size_t)E * 4 + 255) & ~(size_t)255;
    int* rp      = (int*)(ws + off);      off += ((size_t)(N + 1) * 4 + 255) & ~(size_t)255;
    uint16_t* rank = (uint16_t*)(ws + off); off += ((size_t)E * 2 + 255) & ~(size_t)255;
    int* deg     = (int*)(ws + off);      off += ((size_t)N * 4 + 255) & ~(size_t)255;
    int* bsum    = (int*)(ws + off);      off += 512 * 4;
    int* flags   = (int*)(ws + off);      off += 256;
    uint16_t* Wf0 = (uint16_t*)(ws + off); off += 16384 * 2;
    uint16_t* Wf1 = (uint16_t*)(ws + off); off += 16384 * 2;
    uint16_t* Wf2 = (uint16_t*)(ws + off); off += 16384 * 2;
    uint16_t* Wfl = (uint16_t*)(ws + off); off += 6144 * 2;
    float* bc    = (float*)(ws + off);    off += 424 * 4 + 160;
    float* stats = (float*)(ws + off);    off += 768 * 4;   // 3 layers x (sum[128], ssq[128])
    float* part  = (float*)(ws + off);    off += (size_t)agg_blocks * 256 * 4;
    const size_t required = off;

    if (ws_size < required){
        int nwords = out_size / 2;
        k_sentinel<<<(nwords + 255) / 256, 256, 0, stream>>>((uint32_t*)d_out, nwords, 0x40004000u);
        return;
    }

    // ---- flags + zero deg + zero stats (fused), CSR build ----
    k_zf<<<NB + 2, 256, 0, stream>>>(deg, N, (const uint32_t*)x, ei, flags, stats, NB);
    k_deg<<<(E + 255) / 256, 256, 0, stream>>>(ei, E, deg, rank, flags);
    k_scan1<<<NB, 256, 0, stream>>>(deg, N, bsum);
    k_scan2<<<1, 512, 0, stream>>>(bsum, NB, rp, N);
    k_scan3<<<NB, 256, 0, stream>>>(deg, N, bsum, rp);
    k_fill<<<1024, 256, 0, stream>>>(ei, E, rp, rank, col, flags, N);

    // ---- fused conversions / weight prep ----
    k_prep<<<2266, 256, 0, stream>>>(W0, W1, W2, Wl, Wf0, Wf1, Wf2, Wfl,
                                     b0, b1, b2, bl, bc, x, hx, NF, flags);

    const float ninv = 1.0f / (float)N;
    const uint16_t* xr = (const uint16_t*)x;

    // layer 0: Y0 = agg(x) @ W0 + b0  -> ag, stats0
    k_ag<<<agg_blocks, 256, 0, stream>>>(hx, xr, rp, col, ag, Wf0, bc, part, N,
                                         stats, 0, ninv, flags);
    k_red<<<red_blocks, 256, 0, stream>>>(part, agg_blocks, stats);
    // layer 1: Y1 = agg(bn0(Y0)) @ W1 + b1 -> hx, stats1
    k_ag<<<agg_blocks, 256, 0, stream>>>(ag, xr, rp, col, hx, Wf1, bc + 128, part, N,
                                         stats, 1, ninv, flags);
    k_red<<<red_blocks, 256, 0, stream>>>(part, agg_blocks, stats + 256);
    // layer 2: Y2 = agg(bn1(Y1)) @ W2 + b2 -> ag, stats2
    k_ag<<<agg_blocks, 256, 0, stream>>>(hx, xr, rp, col, ag, Wf2, bc + 256, part, N,
                                         stats + 256, 1, ninv, flags);
    k_red<<<red_blocks, 256, 0, stream>>>(part, agg_blocks, stats + 512);
    // final: out = bn2(Y2)relu @ Wl + bl
    k_out<<<gemm_blocks, 256, 0, stream>>>(ag, Wfl, bc + 384, stats + 512, ninv, d_out, N, flags);
}